// Round 6
// baseline (316.296 us; speedup 1.0000x reference)
//
#include <hip/hip_runtime.h>
#include <math.h>

// SPP: out = concat(x, mp5(x), mp9(x), mp13(x)) along channels.
// x: (32, 512, 32, 32) fp32 -> out: (32, 2048, 32, 32) fp32.
// Identities: mp9 = mp5(mp5(x)), mp13 = mp5(mp9(x)); mp5 separable.
//
// Round-5 = Round-4 with the compile fix: __builtin_nontemporal_store
// requires a NATIVE vector pointer, not HIP_vector_type. All nt stores
// go through a clang ext_vector_type(4) alias (same 16B layout).
//
// Memory-path changes under test (R0/R3 identical 135us despite opposite
// schedules => limiter is the memory path, not the schedule):
//   1. ALL output stores nontemporal (nt): 256 MB write stream is never
//      re-read; don't churn L2/L3 with it (keeps x cacheable, avoids
//      write-allocate overhead).
//   2. 4 planes per block, all 4 global loads issued back-to-back at
//      block start: 4x coarser chip-wide read/write interleave (fewer
//      HBM bus turnarounds) and 4x read MLP per wave.
//
// Occupancy: LDS 9216 B; __launch_bounds__(256,7) caps VGPR ~72 -> ~28
// waves/CU.

constexpr int STRF = 36;             // LDS row stride in floats (144 B)
constexpr int PLANE = 32 * STRF;     // 1152 floats = 4608 B per plane

typedef float float4n __attribute__((ext_vector_type(4)));  // native vec4

__device__ __forceinline__ void nt_store4(float4 v, float4* p) {
  float4n w = {v.x, v.y, v.z, v.w};
  __builtin_nontemporal_store(w, (float4n*)p);
}

__device__ __forceinline__ float max5(float a, float b, float c, float d,
                                      float e) {
  return fmaxf(fmaxf(fmaxf(a, b), fmaxf(c, d)), e);
}

__global__ __launch_bounds__(256, 7) void spp_kernel(
    const float* __restrict__ x, float* __restrict__ out) {
  __shared__ __align__(16) float A[PLANE];
  __shared__ __align__(16) float B[PLANE];

  const int t = threadIdx.x;
  const int p0 = blockIdx.x * 4;       // first plane; 4 consecutive planes
  const int n = p0 >> 9;               // same n for all 4 (512 % 4 == 0)
  const int c = p0 & 511;
  const int r = t >> 3;                // row 0..31
  const int c0 = (t & 7) * 4;          // col base 0..28

  const float4* __restrict__ xin = (const float4*)x + (size_t)p0 * 256;
  float4* __restrict__ oid = (float4*)out + ((size_t)n * 2048 + c) * 256;

  // ---- read burst: all 4 planes, back-to-back loads (max MLP) ----
  float4 v0 = xin[t];
  float4 v1 = xin[256 + t];
  float4 v2 = xin[512 + t];
  float4 v3 = xin[768 + t];
  // Identity copies (planes contiguous in out's first 512-ch block), nt.
  nt_store4(v0, &oid[t]);
  nt_store4(v1, &oid[256 + t]);
  nt_store4(v2, &oid[512 + t]);
  nt_store4(v3, &oid[768 + t]);

  // Clamped row indices (duplicates == -inf padding for max).
  const int rm2 = (r < 2) ? 0 : r - 2;
  const int rm1 = (r < 1) ? 0 : r - 1;
  const int rp1 = (r > 30) ? 31 : r + 1;
  const int rp2 = (r > 29) ? 31 : r + 2;
  const bool le = (c0 == 0);
  const bool re = (c0 == 28);

  #pragma unroll
  for (int p = 0; p < 4; ++p) {
    const float4 v = (p == 0) ? v0 : (p == 1) ? v1 : (p == 2) ? v2 : v3;
    *(float4*)(&A[r * STRF + c0]) = v;
    __syncthreads();

    float* cur = A;
    float* nxt = B;
    #pragma unroll
    for (int s = 0; s < 3; ++s) {
      // ---- column pass: 5 row-clamped b128 reads, 4 col-maxes ----
      const float4 u0 = *(const float4*)(cur + rm2 * STRF + c0);
      const float4 u1 = *(const float4*)(cur + rm1 * STRF + c0);
      const float4 u2 = *(const float4*)(cur + r   * STRF + c0);
      const float4 u3 = *(const float4*)(cur + rp1 * STRF + c0);
      const float4 u4 = *(const float4*)(cur + rp2 * STRF + c0);
      const float cm0 = max5(u0.x, u1.x, u2.x, u3.x, u4.x);
      const float cm1 = max5(u0.y, u1.y, u2.y, u3.y, u4.y);
      const float cm2 = max5(u0.z, u1.z, u2.z, u3.z, u4.z);
      const float cm3 = max5(u0.w, u1.w, u2.w, u3.w, u4.w);

      // ---- neighbor columns via shuffle (lane +/-1 == cols +/-4) ----
      const float sl2 = __shfl_up(cm2, 1);    // col c0-2
      const float sl3 = __shfl_up(cm3, 1);    // col c0-1
      const float sr0 = __shfl_down(cm0, 1);  // col c0+4
      const float sr1 = __shfl_down(cm1, 1);  // col c0+5
      const float e0 = le ? -INFINITY : sl2;
      const float e1 = le ? -INFINITY : sl3;
      const float e6 = re ? -INFINITY : sr0;
      const float e7 = re ? -INFINITY : sr1;

      // ---- row pass: 5-wide window per output col ----
      float4 m;
      m.x = max5(e0, e1, cm0, cm1, cm2);
      m.y = max5(e1, cm0, cm1, cm2, cm3);
      m.z = max5(cm0, cm1, cm2, cm3, e6);
      m.w = max5(cm1, cm2, cm3, e6, e7);

      // ---- level store straight from registers, nontemporal ----
      nt_store4(m, &oid[(size_t)(s + 1) * 131072 + (size_t)p * 256 + t]);

      if (s < 2) {
        *(float4*)(&nxt[r * STRF + c0]) = m;  // next stage's input
        __syncthreads();
        float* tmp = cur; cur = nxt; nxt = tmp;  // static after unroll
      }
    }
    // All reads of this plane's LDS done before restaging A.
    __syncthreads();
  }
}

extern "C" void kernel_launch(void* const* d_in, const int* in_sizes, int n_in,
                              void* d_out, int out_size, void* d_ws,
                              size_t ws_size, hipStream_t stream) {
  const float* x = (const float*)d_in[0];
  float* out = (float*)d_out;
  // 16384 planes / (4 planes per block) = 4096 blocks
  spp_kernel<<<4096, 256, 0, stream>>>(x, out);
}

// Round 7
// 303.871 us; speedup vs baseline: 1.0409x; 1.0409x over previous
//
#include <hip/hip_runtime.h>
#include <math.h>

// SPP: out = concat(x, mp5(x), mp9(x), mp13(x)) along channels.
// x: (32, 512, 32, 32) fp32 -> out: (32, 2048, 32, 32) fp32.
//
// Round-6: SINGLE-BARRIER FAN-OUT. R0 and R3 measured bit-identical
// (302.39 us) with opposite schedules -> the per-stage barrier structure
// serializes the pipes (mem 53 + LDS 32 + VALU 21 ~= the observed 137us
// kernel). Fix: compute all three levels DIRECTLY from the staged input
// (mp9 = 9-tap separable, mp13 = 13-tap; incremental column maxes
// cm5 -> cm9 -> cm13 need only 13 ds_read_b128 total), so after ONE
// __syncthreads every wave is an independent read/compute/store stream
// and the HW can overlap global, LDS and VALU across 32 waves/CU.
//   - halo staging (rows -6..37, clamped == -inf pad for max): no
//     row-clamp VALU, all 13 reads are one base + immediate offsets
//   - horizontal passes in registers: neighbor col-maxes via 24 __shfl
//     with row-edge guards; 9/13-wide windows via prefix/suffix chains
//   - levels stored straight from registers (coalesced float4)
// LDS: 44 rows * 36 floats = 6336 B/block. STRF=36 keeps b128 16B-aligned
// and bank-uniform (8 words/bank per wave instruction).

constexpr int STRF = 36;             // LDS row stride in floats
constexpr int HROWS = 44;            // 6 halo + 32 + 6 halo

__device__ __forceinline__ float fmax3(float a, float b, float c) {
  return fmaxf(fmaxf(a, b), c);     // clang fuses to v_max3_f32
}
__device__ __forceinline__ float4 vmax(float4 a, float4 b) {
  return make_float4(fmaxf(a.x, b.x), fmaxf(a.y, b.y), fmaxf(a.z, b.z),
                     fmaxf(a.w, b.w));
}

__global__ __launch_bounds__(256, 8) void spp_kernel(
    const float* __restrict__ x, float* __restrict__ out) {
  __shared__ __align__(16) float A[HROWS * STRF];  // 6336 B

  const int t = threadIdx.x;
  const int plane = blockIdx.x;        // n*512 + c
  const int n = plane >> 9;
  const int c = plane & 511;
  const int r = t >> 3;                // row 0..31
  const int c0 = (t & 7) * 4;          // col base 0..28

  const float4* __restrict__ xin = (const float4*)x + (size_t)plane * 256;
  float4* __restrict__ oid = (float4*)out + ((size_t)n * 2048 + c) * 256;

  // ---- load, identity store, halo-stage ----
  float4 v = xin[t];
  oid[t] = v;
  *(float4*)(&A[(r + 6) * STRF + c0]) = v;   // physical row = logical + 6
  if (r == 0) {
    #pragma unroll
    for (int d = 0; d < 6; ++d) *(float4*)(&A[d * STRF + c0]) = v;
  } else if (r == 31) {
    #pragma unroll
    for (int d = 0; d < 6; ++d) *(float4*)(&A[(38 + d) * STRF + c0]) = v;
  }
  __syncthreads();                     // the ONLY barrier

  // ---- vertical pass: incremental column maxes over 13 halo rows ----
  const float* base = &A[r * STRF + c0];  // physical r == logical r-6
  const float4 u4 = *(const float4*)(base + 4 * STRF);
  const float4 u5 = *(const float4*)(base + 5 * STRF);
  const float4 u6 = *(const float4*)(base + 6 * STRF);
  const float4 u7 = *(const float4*)(base + 7 * STRF);
  const float4 u8 = *(const float4*)(base + 8 * STRF);
  const float4 cm5 = vmax(vmax(vmax(u4, u5), vmax(u6, u7)), u8);
  const float4 u2 = *(const float4*)(base + 2 * STRF);
  const float4 u3 = *(const float4*)(base + 3 * STRF);
  const float4 u9 = *(const float4*)(base + 9 * STRF);
  const float4 u10 = *(const float4*)(base + 10 * STRF);
  const float4 cm9 = vmax(cm5, vmax(vmax(u2, u3), vmax(u9, u10)));
  const float4 u0 = *(const float4*)(base + 0 * STRF);
  const float4 u1 = *(const float4*)(base + 1 * STRF);
  const float4 u11 = *(const float4*)(base + 11 * STRF);
  const float4 u12 = *(const float4*)(base + 12 * STRF);
  const float4 cm13 = vmax(cm9, vmax(vmax(u0, u1), vmax(u11, u12)));

  // Row-edge validity of lane-neighbor shuffles (lane +/-1 == cols +/-4).
  const bool gL1 = (c0 >= 4), gL2 = (c0 >= 8);
  const bool gR1 = (c0 <= 24), gR2 = (c0 <= 20);
  const float NI = -INFINITY;

  // ---- level 1: mp5 (window +/-2) ----
  {
    float a2 = __shfl_up(cm5.z, 1);  a2 = gL1 ? a2 : NI;   // col c0-2
    float a3 = __shfl_up(cm5.w, 1);  a3 = gL1 ? a3 : NI;   // col c0-1
    float b0 = __shfl_down(cm5.x, 1); b0 = gR1 ? b0 : NI;  // col c0+4
    float b1 = __shfl_down(cm5.y, 1); b1 = gR1 ? b1 : NI;  // col c0+5
    float4 m;
    m.x = fmaxf(fmax3(a2, a3, cm5.x), fmaxf(cm5.y, cm5.z));
    m.y = fmaxf(fmax3(a3, cm5.x, cm5.y), fmaxf(cm5.z, cm5.w));
    m.z = fmaxf(fmax3(cm5.x, cm5.y, cm5.z), fmaxf(cm5.w, b0));
    m.w = fmaxf(fmax3(cm5.y, cm5.z, cm5.w), fmaxf(b0, b1));
    oid[131072 + t] = m;             // +512 channels
  }

  // ---- level 2: mp9 (window +/-4) ----
  {
    float L0 = __shfl_up(cm9.x, 1), L1 = __shfl_up(cm9.y, 1);
    float L2 = __shfl_up(cm9.z, 1), L3 = __shfl_up(cm9.w, 1);
    float R0 = __shfl_down(cm9.x, 1), R1 = __shfl_down(cm9.y, 1);
    float R2 = __shfl_down(cm9.z, 1), R3 = __shfl_down(cm9.w, 1);
    L0 = gL1 ? L0 : NI; L1 = gL1 ? L1 : NI;
    L2 = gL1 ? L2 : NI; L3 = gL1 ? L3 : NI;
    R0 = gR1 ? R0 : NI; R1 = gR1 ? R1 : NI;
    R2 = gR1 ? R2 : NI; R3 = gR1 ? R3 : NI;
    const float core = fmaxf(fmaxf(cm9.x, cm9.y), fmaxf(cm9.z, cm9.w));
    const float S3 = L3, S2 = fmaxf(L2, S3), S1 = fmaxf(L1, S2),
                S0 = fmaxf(L0, S1);
    const float P0 = R0, P1 = fmaxf(R1, P0), P2 = fmaxf(R2, P1),
                P3 = fmaxf(R3, P2);
    float4 m;
    m.x = fmax3(S0, core, P0);
    m.y = fmax3(S1, core, P1);
    m.z = fmax3(S2, core, P2);
    m.w = fmax3(S3, core, P3);
    oid[262144 + t] = m;
  }

  // ---- level 3: mp13 (window +/-6) ----
  {
    float L0 = __shfl_up(cm13.x, 1), L1 = __shfl_up(cm13.y, 1);
    float L2 = __shfl_up(cm13.z, 1), L3 = __shfl_up(cm13.w, 1);
    float LL2 = __shfl_up(cm13.z, 2), LL3 = __shfl_up(cm13.w, 2);
    float R0 = __shfl_down(cm13.x, 1), R1 = __shfl_down(cm13.y, 1);
    float R2 = __shfl_down(cm13.z, 1), R3 = __shfl_down(cm13.w, 1);
    float RR0 = __shfl_down(cm13.x, 2), RR1 = __shfl_down(cm13.y, 2);
    L0 = gL1 ? L0 : NI; L1 = gL1 ? L1 : NI;
    L2 = gL1 ? L2 : NI; L3 = gL1 ? L3 : NI;
    LL2 = gL2 ? LL2 : NI; LL3 = gL2 ? LL3 : NI;    // cols c0-6, c0-5
    R0 = gR1 ? R0 : NI; R1 = gR1 ? R1 : NI;
    R2 = gR1 ? R2 : NI; R3 = gR1 ? R3 : NI;
    RR0 = gR2 ? RR0 : NI; RR1 = gR2 ? RR1 : NI;    // cols c0+8, c0+9
    const float core = fmaxf(fmaxf(cm13.x, cm13.y), fmaxf(cm13.z, cm13.w));
    // suffix maxes over [LL2, LL3, L0, L1, L2, L3] (cols c0-6 .. c0-1)
    const float S5 = L3, S4 = fmaxf(L2, S5), S3 = fmaxf(L1, S4),
                S2 = fmaxf(L0, S3), S1 = fmaxf(LL3, S2),
                S0 = fmaxf(LL2, S1);
    // prefix maxes over [R0, R1, R2, R3, RR0, RR1] (cols c0+4 .. c0+9)
    const float P0 = R0, P1 = fmaxf(R1, P0), P2 = fmaxf(R2, P1),
                P3 = fmaxf(R3, P2), P4 = fmaxf(RR0, P3),
                P5 = fmaxf(RR1, P4);
    float4 m;
    m.x = fmax3(S0, core, P2);   // cols c0-6 .. c0+6
    m.y = fmax3(S1, core, P3);   // cols c0-5 .. c0+7
    m.z = fmax3(S2, core, P4);   // cols c0-4 .. c0+8
    m.w = fmax3(S3, core, P5);   // cols c0-3 .. c0+9
    oid[393216 + t] = m;
  }
}

extern "C" void kernel_launch(void* const* d_in, const int* in_sizes, int n_in,
                              void* d_out, int out_size, void* d_ws,
                              size_t ws_size, hipStream_t stream) {
  const float* x = (const float*)d_in[0];
  float* out = (float*)d_out;
  spp_kernel<<<32 * 512, 256, 0, stream>>>(x, out);  // 1 block per plane
}

// Round 8
// 298.059 us; speedup vs baseline: 1.0612x; 1.0195x over previous
//
#include <hip/hip_runtime.h>
#include <math.h>

// SPP: out = concat(x, mp5(x), mp9(x), mp13(x)) along channels.
// x: (32, 512, 32, 32) fp32 -> out: (32, 2048, 32, 32) fp32.
//
// Round-7 = Round-6 (verified, 303.87us) + NONTEMPORAL on both streams.
// Evidence: R0/R3/R6 land at 302.4/302.4/303.9 despite opposite on-chip
// schedules -> schedule is off the critical path; remaining candidate is
// memory-path: all 335 MB of traffic is stream-once (x read once, out
// written once), so L2/L3 line allocation is pure churn. nt loads/stores
// make the kernel a cache-pass-through like a DMA engine. This is the
// clean test R5 confounded (nt + 4-plane batching regression).
//
// Structure (R6): single barrier; all three levels computed directly
// from the halo-staged input plane via incremental column maxes
// (cm5 -> cm9 -> cm13, 13 ds_read_b128 total); horizontal windows in
// registers via __shfl + prefix/suffix max chains; levels stored
// straight from registers. LDS 6336 B; 32 waves/CU.

constexpr int STRF = 36;             // LDS row stride in floats
constexpr int HROWS = 44;            // 6 halo + 32 + 6 halo

typedef float float4n __attribute__((ext_vector_type(4)));  // native vec4

__device__ __forceinline__ float4 nt_load4(const float4* p) {
  float4n w = __builtin_nontemporal_load((const float4n*)p);
  return make_float4(w.x, w.y, w.z, w.w);
}
__device__ __forceinline__ void nt_store4(float4 v, float4* p) {
  float4n w = {v.x, v.y, v.z, v.w};
  __builtin_nontemporal_store(w, (float4n*)p);
}

__device__ __forceinline__ float fmax3(float a, float b, float c) {
  return fmaxf(fmaxf(a, b), c);     // clang fuses to v_max3_f32
}
__device__ __forceinline__ float4 vmax(float4 a, float4 b) {
  return make_float4(fmaxf(a.x, b.x), fmaxf(a.y, b.y), fmaxf(a.z, b.z),
                     fmaxf(a.w, b.w));
}

__global__ __launch_bounds__(256, 8) void spp_kernel(
    const float* __restrict__ x, float* __restrict__ out) {
  __shared__ __align__(16) float A[HROWS * STRF];  // 6336 B

  const int t = threadIdx.x;
  const int plane = blockIdx.x;        // n*512 + c
  const int n = plane >> 9;
  const int c = plane & 511;
  const int r = t >> 3;                // row 0..31
  const int c0 = (t & 7) * 4;          // col base 0..28

  const float4* __restrict__ xin = (const float4*)x + (size_t)plane * 256;
  float4* __restrict__ oid = (float4*)out + ((size_t)n * 2048 + c) * 256;

  // ---- nt load, nt identity store, halo-stage ----
  float4 v = nt_load4(&xin[t]);
  nt_store4(v, &oid[t]);
  *(float4*)(&A[(r + 6) * STRF + c0]) = v;   // physical row = logical + 6
  if (r == 0) {
    #pragma unroll
    for (int d = 0; d < 6; ++d) *(float4*)(&A[d * STRF + c0]) = v;
  } else if (r == 31) {
    #pragma unroll
    for (int d = 0; d < 6; ++d) *(float4*)(&A[(38 + d) * STRF + c0]) = v;
  }
  __syncthreads();                     // the ONLY barrier

  // ---- vertical pass: incremental column maxes over 13 halo rows ----
  const float* base = &A[r * STRF + c0];  // physical r == logical r-6
  const float4 u4 = *(const float4*)(base + 4 * STRF);
  const float4 u5 = *(const float4*)(base + 5 * STRF);
  const float4 u6 = *(const float4*)(base + 6 * STRF);
  const float4 u7 = *(const float4*)(base + 7 * STRF);
  const float4 u8 = *(const float4*)(base + 8 * STRF);
  const float4 cm5 = vmax(vmax(vmax(u4, u5), vmax(u6, u7)), u8);
  const float4 u2 = *(const float4*)(base + 2 * STRF);
  const float4 u3 = *(const float4*)(base + 3 * STRF);
  const float4 u9 = *(const float4*)(base + 9 * STRF);
  const float4 u10 = *(const float4*)(base + 10 * STRF);
  const float4 cm9 = vmax(cm5, vmax(vmax(u2, u3), vmax(u9, u10)));
  const float4 u0 = *(const float4*)(base + 0 * STRF);
  const float4 u1 = *(const float4*)(base + 1 * STRF);
  const float4 u11 = *(const float4*)(base + 11 * STRF);
  const float4 u12 = *(const float4*)(base + 12 * STRF);
  const float4 cm13 = vmax(cm9, vmax(vmax(u0, u1), vmax(u11, u12)));

  // Edge validity of lane-neighbor shuffles (lane +/-1 == cols +/-4).
  const bool gL1 = (c0 >= 4), gL2 = (c0 >= 8);
  const bool gR1 = (c0 <= 24), gR2 = (c0 <= 20);
  const float NI = -INFINITY;

  // ---- level 1: mp5 (window +/-2) ----
  {
    float a2 = __shfl_up(cm5.z, 1);  a2 = gL1 ? a2 : NI;   // col c0-2
    float a3 = __shfl_up(cm5.w, 1);  a3 = gL1 ? a3 : NI;   // col c0-1
    float b0 = __shfl_down(cm5.x, 1); b0 = gR1 ? b0 : NI;  // col c0+4
    float b1 = __shfl_down(cm5.y, 1); b1 = gR1 ? b1 : NI;  // col c0+5
    float4 m;
    m.x = fmaxf(fmax3(a2, a3, cm5.x), fmaxf(cm5.y, cm5.z));
    m.y = fmaxf(fmax3(a3, cm5.x, cm5.y), fmaxf(cm5.z, cm5.w));
    m.z = fmaxf(fmax3(cm5.x, cm5.y, cm5.z), fmaxf(cm5.w, b0));
    m.w = fmaxf(fmax3(cm5.y, cm5.z, cm5.w), fmaxf(b0, b1));
    nt_store4(m, &oid[131072 + t]);  // +512 channels
  }

  // ---- level 2: mp9 (window +/-4) ----
  {
    float L0 = __shfl_up(cm9.x, 1), L1 = __shfl_up(cm9.y, 1);
    float L2 = __shfl_up(cm9.z, 1), L3 = __shfl_up(cm9.w, 1);
    float R0 = __shfl_down(cm9.x, 1), R1 = __shfl_down(cm9.y, 1);
    float R2 = __shfl_down(cm9.z, 1), R3 = __shfl_down(cm9.w, 1);
    L0 = gL1 ? L0 : NI; L1 = gL1 ? L1 : NI;
    L2 = gL1 ? L2 : NI; L3 = gL1 ? L3 : NI;
    R0 = gR1 ? R0 : NI; R1 = gR1 ? R1 : NI;
    R2 = gR1 ? R2 : NI; R3 = gR1 ? R3 : NI;
    const float core = fmaxf(fmaxf(cm9.x, cm9.y), fmaxf(cm9.z, cm9.w));
    const float S3 = L3, S2 = fmaxf(L2, S3), S1 = fmaxf(L1, S2),
                S0 = fmaxf(L0, S1);
    const float P0 = R0, P1 = fmaxf(R1, P0), P2 = fmaxf(R2, P1),
                P3 = fmaxf(R3, P2);
    float4 m;
    m.x = fmax3(S0, core, P0);
    m.y = fmax3(S1, core, P1);
    m.z = fmax3(S2, core, P2);
    m.w = fmax3(S3, core, P3);
    nt_store4(m, &oid[262144 + t]);
  }

  // ---- level 3: mp13 (window +/-6) ----
  {
    float L0 = __shfl_up(cm13.x, 1), L1 = __shfl_up(cm13.y, 1);
    float L2 = __shfl_up(cm13.z, 1), L3 = __shfl_up(cm13.w, 1);
    float LL2 = __shfl_up(cm13.z, 2), LL3 = __shfl_up(cm13.w, 2);
    float R0 = __shfl_down(cm13.x, 1), R1 = __shfl_down(cm13.y, 1);
    float R2 = __shfl_down(cm13.z, 1), R3 = __shfl_down(cm13.w, 1);
    float RR0 = __shfl_down(cm13.x, 2), RR1 = __shfl_down(cm13.y, 2);
    L0 = gL1 ? L0 : NI; L1 = gL1 ? L1 : NI;
    L2 = gL1 ? L2 : NI; L3 = gL1 ? L3 : NI;
    LL2 = gL2 ? LL2 : NI; LL3 = gL2 ? LL3 : NI;    // cols c0-6, c0-5
    R0 = gR1 ? R0 : NI; R1 = gR1 ? R1 : NI;
    R2 = gR1 ? R2 : NI; R3 = gR1 ? R3 : NI;
    RR0 = gR2 ? RR0 : NI; RR1 = gR2 ? RR1 : NI;    // cols c0+8, c0+9
    const float core = fmaxf(fmaxf(cm13.x, cm13.y), fmaxf(cm13.z, cm13.w));
    const float S5 = L3, S4 = fmaxf(L2, S5), S3 = fmaxf(L1, S4),
                S2 = fmaxf(L0, S3), S1 = fmaxf(LL3, S2),
                S0 = fmaxf(LL2, S1);
    const float P0 = R0, P1 = fmaxf(R1, P0), P2 = fmaxf(R2, P1),
                P3 = fmaxf(R3, P2), P4 = fmaxf(RR0, P3),
                P5 = fmaxf(RR1, P4);
    float4 m;
    m.x = fmax3(S0, core, P2);   // cols c0-6 .. c0+6
    m.y = fmax3(S1, core, P3);   // cols c0-5 .. c0+7
    m.z = fmax3(S2, core, P4);   // cols c0-4 .. c0+8
    m.w = fmax3(S3, core, P5);   // cols c0-3 .. c0+9
    nt_store4(m, &oid[393216 + t]);
  }
}

extern "C" void kernel_launch(void* const* d_in, const int* in_sizes, int n_in,
                              void* d_out, int out_size, void* d_ws,
                              size_t ws_size, hipStream_t stream) {
  const float* x = (const float*)d_in[0];
  float* out = (float*)d_out;
  spp_kernel<<<32 * 512, 256, 0, stream>>>(x, out);  // 1 block per plane
}